// Round 9
// baseline (245.055 us; speedup 1.0000x reference)
//
#include <hip/hip_runtime.h>

typedef unsigned short u16;
typedef unsigned int u32;
typedef __attribute__((ext_vector_type(8))) short short8;
typedef __attribute__((ext_vector_type(8))) __bf16 bf16x8;
typedef __attribute__((ext_vector_type(4))) float f32x4;
typedef __attribute__((ext_vector_type(16))) float f32x16;

__device__ __forceinline__ u16 f2bf(float f) {
  union { float f; u32 u; } c; c.f = f;
  u32 u = c.u + 0x7fffu + ((c.u >> 16) & 1u);  // round-to-nearest-even
  return (u16)(u >> 16);
}
__device__ __forceinline__ f32x4 mfma16(short8 a, short8 b, f32x4 c) {
  return __builtin_amdgcn_mfma_f32_16x16x32_bf16(
      __builtin_bit_cast(bf16x8, a), __builtin_bit_cast(bf16x8, b), c, 0, 0, 0);
}
__device__ __forceinline__ f32x16 mfma32(short8 a, short8 b, f32x16 c) {
  return __builtin_amdgcn_mfma_f32_32x32x16_bf16(
      __builtin_bit_cast(bf16x8, a), __builtin_bit_cast(bf16x8, b), c, 0, 0, 0);
}
__device__ __forceinline__ float fexp2(float x) {   // guaranteed single v_exp_f32
  float r; asm("v_exp_f32 %0, %1" : "=v"(r) : "v"(x)); return r;
}
// async global->LDS: per-LANE global src, wave-uniform LDS base (HW adds lane*16)
__device__ __forceinline__ void gl16(const u16* g, u16* l) {
  __builtin_amdgcn_global_load_lds(
      (const __attribute__((address_space(1))) unsigned*)g,
      (__attribute__((address_space(3))) unsigned*)l, 16, 0, 0);
}

// ============ Tiled K / V^T global layout (per (b,h) slice: 32 tiles x 8 segs x 1KB) ==
// K  seg s, lane l (l31=l&31, hi=l>>5): K[t0+(s&1)*32+l31][h*64+(s>>1)*16+hi*8+j]
// V  seg s, lane l:                  V^T[h*64+(s&1)*32+l31][t0+(s>>1)*16+hi*8+j]
// u16 addr = ((b*16+h)*32 + tile)*4096 + s*512 + l*8 + j.

// ---------------- transpose+convert: out_bf16[C][R] = in_f32[R][C] ----------------
__global__ __launch_bounds__(256) void transpose_f32_bf16(const float* __restrict__ in,
                                                          u16* __restrict__ out,
                                                          int R, int C) {
  __shared__ u16 tile[32][33];
  int tx = threadIdx.x & 31, ty = threadIdx.x >> 5;
  int c0 = blockIdx.x * 32, r0 = blockIdx.y * 32;
  for (int i = 0; i < 32; i += 8)
    tile[ty + i][tx] = f2bf(in[(size_t)(r0 + ty + i) * C + c0 + tx]);
  __syncthreads();
  for (int i = 0; i < 32; i += 8)
    out[(size_t)(c0 + ty + i) * R + r0 + tx] = tile[tx][ty + i];
}

// ---------------- convert: out_bf16[i] = bf16(in_f32[i]), 8 elems/thread ----------------
__global__ __launch_bounds__(256) void f32_to_bf16(const float* __restrict__ in,
                                                   u16* __restrict__ out) {
  const size_t base = ((size_t)blockIdx.x * 256 + threadIdx.x) * 8;
  float4 f0 = *(const float4*)(in + base);
  float4 f1 = *(const float4*)(in + base + 4);
  short8 v;
  v[0] = (short)f2bf(f0.x); v[1] = (short)f2bf(f0.y);
  v[2] = (short)f2bf(f0.z); v[3] = (short)f2bf(f0.w);
  v[4] = (short)f2bf(f1.x); v[5] = (short)f2bf(f1.y);
  v[6] = (short)f2bf(f1.z); v[7] = (short)f2bf(f1.w);
  *(short8*)&out[base] = v;
}

// ---- GEMM: C = A[M][K] @ BT[N][K]^T, frag-major gl16 staging, 2-phase dbuf ----
// MODE 0: A16/B16, no bias, f32 out ldc=N               (out-proj, BM=64)
// MODE 1: A16/B16, col-bias; n<1024 -> Q row-major; else -> K TILED (BM=64)
// MODE 2: A16/Bf32(f2bf cvt), ROW-bias, out = V^T TILED (V^T = WvT @ X^T, BM=64)
template <int MODE, int BM>
__global__ __launch_bounds__(256) void gemm_bt(const void* __restrict__ Av,
                                               const void* __restrict__ Bv,
                                               const float* __restrict__ bias,
                                               void* __restrict__ C0v,
                                               void* __restrict__ C1v,
                                               int M, int N, int K) {
  constexpr int MI  = BM / 32;           // acc rows per wave
  constexpr int NSA = BM / 8;            // A frag segments
  constexpr int ASZ = NSA * 512;
  constexpr int BSZ = (MODE == 2) ? 9216 : 8192;
  __shared__ __align__(16) u16 As[2][ASZ];
  __shared__ __align__(16) u16 Bs[2][BSZ];
  const int tid = threadIdx.x;
  const int w = tid >> 6, l = tid & 63;
  const int i16 = l & 15, q4 = l >> 4;

  // XCD-chunked swizzle (all grids have nwg % 8 == 0)
  const int nbx = gridDim.x;
  const int nwg = nbx * gridDim.y;
  int fid = blockIdx.y * nbx + blockIdx.x;
  int wg = (nwg & 7) ? fid : ((fid & 7) * (nwg >> 3) + (fid >> 3));
  const int m0 = (wg / nbx) * BM, n0 = (wg % nbx) * 128;
  const int wm = (w >> 1) * (BM / 2), wn = (w & 1) * 64;

  const int arow = tid >> 3, akg = (tid & 7) * 8;  // fp32 reg-stage geometry

  const u16* A16p = (const u16*)Av;
  const u16* B16p = (const u16*)Bv;
  const float* Fp = (const float*)Bv;              // MODE 2 only
  const int fbase = n0;

  f32x4 acc[MI][4] = {};
  float4 pf[4][2];

#define STAGE_A16(bufi, kk) {                                                  \
    _Pragma("unroll") for (int i = 0; i < NSA / 4; ++i) {                      \
      const int s = w * (NSA / 4) + i;                                         \
      gl16(&A16p[(size_t)(m0 + (s >> 1) * 16 + i16) * K + (kk) + (s & 1) * 32  \
                 + q4 * 8],                                                    \
           &As[bufi][s * 512]); } }
#define STAGE_B16(bufi, kk) {                                                  \
    _Pragma("unroll") for (int i = 0; i < 4; ++i) {                            \
      const int s = w * 4 + i;                                                 \
      gl16(&B16p[(size_t)(n0 + (s >> 1) * 16 + i16) * K + (kk) + (s & 1) * 32  \
                 + q4 * 8],                                                    \
           &Bs[bufi][s * 512]); } }
#define LOAD_PFX(kk) {                                                         \
    _Pragma("unroll") for (int i = 0; i < 4; ++i) {                            \
      const float* src = Fp + (size_t)(fbase + arow + i * 32) * K + (kk) + akg;\
      pf[i][0] = *(const float4*)src;                                          \
      pf[i][1] = *(const float4*)(src + 4); } }
#define CVT_X(bufi) {                                                          \
    _Pragma("unroll") for (int i = 0; i < 4; ++i) {                            \
      short8 v;                                                                \
      v[0] = (short)f2bf(pf[i][0].x); v[1] = (short)f2bf(pf[i][0].y);          \
      v[2] = (short)f2bf(pf[i][0].z); v[3] = (short)f2bf(pf[i][0].w);          \
      v[4] = (short)f2bf(pf[i][1].x); v[5] = (short)f2bf(pf[i][1].y);          \
      v[6] = (short)f2bf(pf[i][1].z); v[7] = (short)f2bf(pf[i][1].w);          \
      *(short8*)&Bs[bufi][(arow + i * 32) * 72 + akg] = v; } }

  const int nk = K >> 6;
  // prologue: tile 0 -> buf 0
  if constexpr (MODE == 2) {
    LOAD_PFX(0); STAGE_A16(0, 0); CVT_X(0); LOAD_PFX(64);
  } else {
    STAGE_A16(0, 0); STAGE_B16(0, 0);
  }
  __syncthreads();

  for (int t = 0; t < nk; ++t) {
    const int cur = t & 1, nxt = cur ^ 1;
    const int k1 = (t + 1) << 6;
    if (t + 1 < nk) {
      if constexpr (MODE == 2) {
        STAGE_A16(nxt, k1); CVT_X(nxt);
        if (t + 2 < nk) LOAD_PFX(k1 + 64);
      } else {
        STAGE_A16(nxt, k1); STAGE_B16(nxt, k1);
      }
    }
#pragma unroll
    for (int ks = 0; ks < 2; ++ks) {
      short8 af[MI], bfr[4];
#pragma unroll
      for (int mi = 0; mi < MI; ++mi)
        af[mi] = *(short8*)((char*)&As[cur][0] +
                            (((wm >> 4) + mi) * 2 + ks) * 1024 + l * 16);
#pragma unroll
      for (int ni = 0; ni < 4; ++ni) {
        if constexpr (MODE == 2)
          bfr[ni] = *(short8*)&Bs[cur][(wn + ni * 16 + i16) * 72 + ks * 32 + q4 * 8];
        else
          bfr[ni] = *(short8*)((char*)&Bs[cur][0] +
                               (((wn >> 4) + ni) * 2 + ks) * 1024 + l * 16);
      }
#pragma unroll
      for (int mi = 0; mi < MI; ++mi)
#pragma unroll
        for (int ni = 0; ni < 4; ++ni)
          acc[mi][ni] = mfma16(af[mi], bfr[ni], acc[mi][ni]);
    }
    __syncthreads();
  }
#undef STAGE_A16
#undef STAGE_B16
#undef LOAD_PFX
#undef CVT_X

  if constexpr (MODE == 0) {
    float* dstf = (float*)C0v;
    for (int mi = 0; mi < MI; ++mi) {
      int row = m0 + wm + mi * 16 + q4 * 4;
      for (int ni = 0; ni < 4; ++ni) {
        int nl = wn + ni * 16 + i16;
        for (int r = 0; r < 4; ++r)
          dstf[(size_t)(row + r) * N + n0 + nl] = acc[mi][ni][r];
      }
    }
  } else if constexpr (MODE == 1) {
    if (n0 < 1024) {                       // Q: row-major bf16 (UNSCALED, as R7)
      u16* dstb = (u16*)C0v;
      for (int mi = 0; mi < MI; ++mi) {
        int row = m0 + wm + mi * 16 + q4 * 4;
        for (int ni = 0; ni < 4; ++ni) {
          int nl = wn + ni * 16 + i16;
          float b = bias[n0 + nl];
          for (int r = 0; r < 4; ++r)
            dstb[(size_t)(row + r) * 1024 + n0 + nl] = f2bf(acc[mi][ni][r] + b);
        }
      }
    } else {                               // K: tiled layout
      u16* KT = (u16*)C1v;
      for (int mi = 0; mi < MI; ++mi) {
        int row = m0 + wm + mi * 16 + q4 * 4;
        for (int ni = 0; ni < 4; ++ni) {
          int nl = wn + ni * 16 + i16;
          const int d = (n0 - 1024) + nl;
          const int hh = d >> 6, dh = d & 63;
          const int sd = (dh >> 4) << 1;          // s = sd + tb
          const int lh = ((dh >> 3) & 1) << 5;    // lane hi*32
          const int j = dh & 7;
          float b = bias[n0 + nl];
          for (int r = 0; r < 4; ++r) {
            const int tok = row + r;
            const int bb = tok >> 11, t = tok & 2047;
            size_t addr = ((size_t)((bb << 4) + hh) * 32 + (t >> 6)) * 4096
                        + (sd + ((t >> 5) & 1)) * 512 + (lh + (t & 31)) * 8 + j;
            KT[addr] = f2bf(acc[mi][ni][r] + b);
          }
        }
      }
    }
  } else {                                 // MODE 2: V^T tiled
    u16* VTt = (u16*)C0v;
    for (int mi = 0; mi < MI; ++mi) {
      int drow = m0 + wm + mi * 16 + q4 * 4;
      float4 bv = *(const float4*)&bias[drow];   // row-bias b_v[d], 4-aligned
      const float bvr[4] = {bv.x, bv.y, bv.z, bv.w};
      for (int ni = 0; ni < 4; ++ni) {
        int col = n0 + wn + ni * 16 + i16;       // global token (incl batch)
        const int bb = col >> 11, t = col & 2047;
        const int su = ((t >> 4) & 3) << 1;      // s = su + (dh>>5)
        const int lt = ((t >> 3) & 1) << 5;      // lane hi*32
        const int j = t & 7;
        const size_t tb0 = ((size_t)(bb << 4) * 32 + (t >> 6)) * 4096;
        for (int r = 0; r < 4; ++r) {
          const int d = drow + r;
          const int hh = d >> 6, dh = d & 63;
          size_t addr = tb0 + (size_t)hh * 131072
                      + (su + (dh >> 5)) * 512 + (lt + (dh & 31)) * 8 + j;
          VTt[addr] = f2bf(acc[mi][ni][r] + bvr[r]);
        }
      }
    }
  }
}

// ---- flash attention: EXACT R7 numerics (fma softmax, unscaled Q) + T5 setprio ----
__global__ __launch_bounds__(512, 4) void attn_flash(u16* __restrict__ Qbuf,
                                                     const u16* __restrict__ Kall,
                                                     const u16* __restrict__ VTall) {
  constexpr float CSC = 0.18033688011112042f;   // log2(e)/sqrt(64)
  constexpr float MC  = 96.0f * CSC;            // fixed max (raw units) * CSC
  __shared__ __align__(16) u16 SH[32768];       // 64 KB staging ∪ 36864 B merge
  __shared__ float RsumB[128], RsumT[128];

  const int tid = threadIdx.x;
  const int w = tid >> 6, l = tid & 63;
  const int l31 = l & 31, hi = l >> 5;
  const int qg = w >> 1, th = w & 1;

  u16* KsL = SH + th * 16384;        // [2 buf][8 seg][512] u16
  u16* VsL = SH + th * 16384 + 8192; // [2 buf][8 seg][512] u16

  const int L = blockIdx.x;
  const int xcd = L & 7, rr = L >> 3;
  const int qb = rr & 15, gg = rr >> 4;
  const int g = gg * 8 + xcd;                   // 0..31 bijective
  const int h = g & 15, bat = g >> 4;
  const int q0 = qb * 128;

  u16* Q = Qbuf + (size_t)bat * 2048 * 1024;
  const u16* ksrc = Kall + (size_t)((bat << 4) + h) * 131072 + l * 8;
  const u16* vsrc = VTall + (size_t)((bat << 4) + h) * 131072 + l * 8;

  // Q fragments (B-operand, loop-invariant, registers)
  short8 qf[4];
  {
    const u16* qrow = Q + (size_t)(q0 + qg * 32 + l31) * 1024 + h * 64 + hi * 8;
#pragma unroll
    for (int ks = 0; ks < 4; ++ks) qf[ks] = *(const short8*)(qrow + ks * 16);
  }

#define STAGE(buf_, it_) {                                                   \
    const size_t toff = (size_t)(it_) * 4096;                                \
    gl16(ksrc + toff + qg * 512,       KsL + (buf_) * 4096 + qg * 512);      \
    gl16(ksrc + toff + (qg + 4) * 512, KsL + (buf_) * 4096 + (qg + 4) * 512);\
    gl16(vsrc + toff + qg * 512,       VsL + (buf_) * 4096 + qg * 512);      \
    gl16(vsrc + toff + (qg + 4) * 512, VsL + (buf_) * 4096 + (qg + 4) * 512); }

  f32x16 o0 = {}, o1 = {};
  float sm0 = 0.f, sm1 = 0.f, sm2 = 0.f, sm3 = 0.f;

  const int tbase = th * 16;                    // tile index base
  STAGE(0, tbase);
  __syncthreads();

  for (int i = 0; i < 16; ++i) {
    const int cur = i & 1;
    if (i + 1 < 16) STAGE(cur ^ 1, tbase + i + 1);

    const char* Kc = (const char*)KsL + cur * 8192 + l * 16;
    const char* Vc = (const char*)VsL + cur * 8192 + l * 16;

    // S^T = K @ Q^T : st{0,1}[reg] = S[q=l31][t = Tb*32 + (reg&3)+8*(reg>>2)+4*hi]
    f32x16 st0 = {}, st1 = {};
    __builtin_amdgcn_s_setprio(1);
#pragma unroll
    for (int ks = 0; ks < 4; ++ks) {
      short8 kf0 = *(const short8*)(Kc + ks * 2048);
      short8 kf1 = *(const short8*)(Kc + ks * 2048 + 1024);
      st0 = mfma32(kf0, qf[ks], st0);
      st1 = mfma32(kf1, qf[ks], st1);
    }
    __builtin_amdgcn_s_setprio(0);

    // softmax numerator p = 2^(s*CSC - MC); row-sum; pack bf16 pairs.
    u32 W[16];
#define SOFTMAX_PACK(stt, WB) {                                             \
      float p_[16];                                                         \
      _Pragma("unroll") for (int r = 0; r < 16; ++r)                        \
          p_[r] = fexp2(__builtin_fmaf(stt[r], CSC, -MC));                  \
      _Pragma("unroll") for (int r = 0; r < 16; r += 4) {                   \
        sm0 += p_[r]; sm1 += p_[r + 1]; sm2 += p_[r + 2]; sm3 += p_[r + 3]; \
      }                                                                     \
      _Pragma("unroll") for (int m = 0; m < 4; ++m)                         \
        _Pragma("unroll") for (int s = 0; s < 2; ++s)                       \
          asm("v_cvt_pk_bf16_f32 %0, %1, %2"                                \
              : "=v"(W[(WB) + m * 2 + s])                                   \
              : "v"(p_[4 * m + 2 * s]), "v"(p_[4 * m + 2 * s + 1]));        \
    }
    SOFTMAX_PACK(st0, 0)
    SOFTMAX_PACK(st1, 8)
#undef SOFTMAX_PACK

    // O += P @ V ; A-frag for t-step u via permlane32_swap of packed pairs
    __builtin_amdgcn_s_setprio(1);
#pragma unroll
    for (int u = 0; u < 4; ++u) {
      const int base = (u >> 1) * 8 + (u & 1) * 4;
      u32 a0 = W[base], a1 = W[base + 1], b0 = W[base + 2], b1 = W[base + 3];
      asm("v_permlane32_swap_b32 %0, %1" : "+v"(a0), "+v"(b0));
      asm("v_permlane32_swap_b32 %0, %1" : "+v"(a1), "+v"(b1));
      int4 af4;
      af4.x = (int)a0; af4.y = (int)a1; af4.z = (int)b0; af4.w = (int)b1;
      const short8 pfr = __builtin_bit_cast(short8, af4);
      const short8 vf0 = *(const short8*)(Vc + u * 2048);
      const short8 vf1 = *(const short8*)(Vc + u * 2048 + 1024);
      o0 = mfma32(pfr, vf0, o0);
      o1 = mfma32(pfr, vf1, o1);
    }
    __builtin_amdgcn_s_setprio(0);
    __syncthreads();   // drains next-tile gl16 (in flight all compute) + buf reuse
  }
#undef STAGE

  // ---- split-t merge: O = O_th0 + O_th1, rs = rs0 + rs1 (fixed max => pure add) ----
  float rs = (sm0 + sm1) + (sm2 + sm3);
  rs += __shfl_xor(rs, 32);
  __syncthreads();                                // staging LDS now dead
  float* MF = (float*)SH;                         // 256 lanes * 36 floats = 36864 B
  if (th == 1) {
    float* dst = MF + (qg * 64 + l) * 36;
    *(f32x16*)dst = o0;
    *(f32x16*)(dst + 16) = o1;
    if (hi == 0) RsumB[qg * 32 + l31] = rs;
  }
  __syncthreads();
  if (th == 0) {
    const float* src = MF + (qg * 64 + l) * 36;
    o0 += *(const f32x16*)src;
    o1 += *(const f32x16*)(src + 16);
    float rtot = rs + RsumB[qg * 32 + l31];
    if (hi == 0) RsumT[qg * 32 + l31] = rtot;
  }
  __syncthreads();
  if (th == 0) {
#pragma unroll
    for (int r = 0; r < 16; ++r) {
      const int qq = (r & 3) + 8 * (r >> 2) + 4 * hi;
      const float inv = 1.0f / RsumT[qg * 32 + qq];
      u16* dst = Q + (size_t)(q0 + qg * 32 + qq) * 1024 + h * 64 + l31;
      dst[0]  = f2bf(o0[r] * inv);
      dst[32] = f2bf(o1[r] * inv);
    }
  }
}

// ---------------- launcher ----------------
// inputs fp32: X [4096][1024], Wqkv [1024][3072], bqkv [3072], Wout [1024][1024]
// d_out (16 MB): [0,8M) Q/O bf16 | [8,14M) WT1 | [14,16M) WT2
// ws (16 MB): [0,8M) Xbf (dies after QK; V^T tiled overwrites) | [8,16M) K tiled;
//             whole ws reused as fp32 C [4096][1024] after attention.
extern "C" void kernel_launch(void* const* d_in, const int* in_sizes, int n_in,
                              void* d_out, int out_size, void* d_ws, size_t ws_size,
                              hipStream_t stream) {
  const float* X    = (const float*)d_in[0];
  const float* Wqkv = (const float*)d_in[1];
  const float* bqkv = (const float*)d_in[2];
  const float* Wout = (const float*)d_in[3];

  u16* Qbuf = (u16*)d_out;                       // [4096][1024] bf16
  u16* WT1  = Qbuf + (size_t)4096 * 1024;        // [3072][1024] bf16 (Wqkv^T)
  u16* WT2  = WT1 + (size_t)3072 * 1024;         // [1024][1024] bf16 (Wout^T)
  u16* Xbf  = (u16*)d_ws;                        // [4096][1024] bf16 (dies after QK)
  u16* Kt   = (u16*)d_ws + (size_t)4096 * 1024;  // K tiled, 8 MB
  u16* VTt  = (u16*)d_ws;                        // V^T tiled, overwrites Xbf
  float* Cws = (float*)d_ws;                     // [4096][1024] f32 (after attn)

  transpose_f32_bf16<<<dim3(96, 32), 256, 0, stream>>>(Wqkv, WT1, 1024, 3072);
  transpose_f32_bf16<<<dim3(32, 32), 256, 0, stream>>>(Wout, WT2, 1024, 1024);
  f32_to_bf16<<<dim3(2048), 256, 0, stream>>>(X, Xbf);

  // QK: [4096][2048] = Xbf @ Wqk (bf16 x bf16; Q row-major, K tiled)
  gemm_bt<1, 64><<<dim3(16, 64), 256, 0, stream>>>(
      Xbf, WT1, bqkv, Qbuf, Kt, 4096, 2048, 1024);

  // V^T: [1024][4096] = Wv^T @ X^T (fp32 X reg-staged; tiled out over dead Xbf)
  gemm_bt<2, 64><<<dim3(32, 16), 256, 0, stream>>>(
      WT1 + (size_t)2048 * 1024, X, bqkv + 2048, VTt, nullptr, 1024, 4096, 1024);

  attn_flash<<<dim3(512), 512, 0, stream>>>(Qbuf, Kt, VTt);

  gemm_bt<0, 64><<<dim3(8, 64), 256, 0, stream>>>(
      Qbuf, WT2, nullptr, Cws, nullptr, 4096, 1024, 1024);

  hipMemcpyAsync(d_out, Cws, (size_t)4096 * 1024 * sizeof(float),
                 hipMemcpyDeviceToDevice, stream);
}

// Round 10
// 213.704 us; speedup vs baseline: 1.1467x; 1.1467x over previous
//
#include <hip/hip_runtime.h>

typedef unsigned short u16;
typedef unsigned int u32;
typedef __attribute__((ext_vector_type(8))) short short8;
typedef __attribute__((ext_vector_type(8))) __bf16 bf16x8;
typedef __attribute__((ext_vector_type(4))) float f32x4;
typedef __attribute__((ext_vector_type(16))) float f32x16;

__device__ __forceinline__ u16 f2bf(float f) {
  union { float f; u32 u; } c; c.f = f;
  u32 u = c.u + 0x7fffu + ((c.u >> 16) & 1u);  // round-to-nearest-even
  return (u16)(u >> 16);
}
__device__ __forceinline__ f32x4 mfma16(short8 a, short8 b, f32x4 c) {
  return __builtin_amdgcn_mfma_f32_16x16x32_bf16(
      __builtin_bit_cast(bf16x8, a), __builtin_bit_cast(bf16x8, b), c, 0, 0, 0);
}
__device__ __forceinline__ f32x16 mfma32(short8 a, short8 b, f32x16 c) {
  return __builtin_amdgcn_mfma_f32_32x32x16_bf16(
      __builtin_bit_cast(bf16x8, a), __builtin_bit_cast(bf16x8, b), c, 0, 0, 0);
}
__device__ __forceinline__ float fexp2(float x) {   // guaranteed single v_exp_f32
  float r; asm("v_exp_f32 %0, %1" : "=v"(r) : "v"(x)); return r;
}
// async global->LDS: per-LANE global src, wave-uniform LDS base (HW adds lane*16)
__device__ __forceinline__ void gl16(const u16* g, u16* l) {
  __builtin_amdgcn_global_load_lds(
      (const __attribute__((address_space(1))) unsigned*)g,
      (__attribute__((address_space(3))) unsigned*)l, 16, 0, 0);
}

// ===== Frag-major 8KB tile layout (64 rows x 64 cols bf16) used for Q/O, K, V^T =====
// tile = 8 segs x 512 u16. Element (row r, col c) in-tile:
//   seg s = ((r&63)>>4)*2 + ((c&63)>>5); slot = (r&15) + (((c&31)>>3)<<4); j = c&7
//   u16 offset = s*512 + slot*8 + j.
// Q/O over [4096 tok][1024 d]: tile index = (tok>>6)*16 + (d>>6).
// K  over per-(b,h): addr = ((b*16+h)*32 + (t>>6))*4096 + in-tile(t, dh).
// V^T per-(b,h):     addr = ((b*16+h)*32 + (t>>6))*4096 + s*512 + slot*8 + j with
//   s = ((t&63)>>4)*2 + (dh>>5); slot = (((t>>3)&1)<<5 | (dh&31)); j = t&7.  (R7-verified)

// ---------------- transpose+convert: out_bf16[C][R] = in_f32[R][C] ----------------
__global__ __launch_bounds__(256) void transpose_f32_bf16(const float* __restrict__ in,
                                                          u16* __restrict__ out,
                                                          int R, int C) {
  __shared__ u16 tile[32][33];
  int tx = threadIdx.x & 31, ty = threadIdx.x >> 5;
  int c0 = blockIdx.x * 32, r0 = blockIdx.y * 32;
  for (int i = 0; i < 32; i += 8)
    tile[ty + i][tx] = f2bf(in[(size_t)(r0 + ty + i) * C + c0 + tx]);
  __syncthreads();
  for (int i = 0; i < 32; i += 8)
    out[(size_t)(c0 + ty + i) * R + r0 + tx] = tile[tx][ty + i];
}

// ---- GEMM: C = A[M][K] @ BT[N][K]^T, 2-phase dbuf ----
// MODE 0 (out-proj, BM=64): A = O in TILED layout -> contiguous 1KB gl16 segs;
//   B bf16 strided frag-major gl16; out f32 row-major ldc=N.
// MODE 1 (fused QKV, BM=128): A = X fp32 reg-staged (padded-72 LDS, R7-proven);
//   B bf16 strided frag-major gl16; col-bias; epilogue routes:
//   n<1024 -> Q TILED | 1024..2047 -> K TILED | >=2048 -> V^T TILED.
template <int MODE, int BM>
__global__ __launch_bounds__(256) void gemm_bt(const void* __restrict__ Av,
                                               const u16* __restrict__ Bv,
                                               const float* __restrict__ bias,
                                               void* __restrict__ C0v,
                                               void* __restrict__ C1v,
                                               void* __restrict__ C2v,
                                               int M, int N, int K) {
  constexpr int MI  = BM / 32;           // acc rows per wave
  constexpr int NSA = BM / 8;            // A frag segments (MODE 0)
  constexpr int ASZ = (MODE == 1) ? 9216 : NSA * 512;
  __shared__ __align__(16) u16 As[2][ASZ];
  __shared__ __align__(16) u16 Bs[2][8192];
  const int tid = threadIdx.x;
  const int w = tid >> 6, l = tid & 63;
  const int i16 = l & 15, q4 = l >> 4;

  // XCD-chunked swizzle (all grids have nwg % 8 == 0)
  const int nbx = gridDim.x;
  const int nwg = nbx * gridDim.y;
  int fid = blockIdx.y * nbx + blockIdx.x;
  int wg = (nwg & 7) ? fid : ((fid & 7) * (nwg >> 3) + (fid >> 3));
  const int m0 = (wg / nbx) * BM, n0 = (wg % nbx) * 128;
  const int wm = (w >> 1) * (BM / 2), wn = (w & 1) * 64;

  const int arow = tid >> 3, akg = (tid & 7) * 8;  // fp32 reg-stage geometry

  const u16* A16p = (const u16*)Av;      // MODE 0: tiled O
  const float* Fp = (const float*)Av;    // MODE 1: fp32 X
  f32x4 acc[MI][4] = {};
  float4 pf[4][2];

#define STAGE_A16(bufi, kk) {                                                  \
    _Pragma("unroll") for (int i = 0; i < NSA / 4; ++i) {                      \
      const int s = w * (NSA / 4) + i;                                         \
      gl16(&A16p[((size_t)((m0 >> 6) * 16 + ((kk) >> 6))) * 4096 + s * 512     \
                 + l * 8],                                                     \
           &As[bufi][s * 512]); } }
#define STAGE_B16(bufi, kk) {                                                  \
    _Pragma("unroll") for (int i = 0; i < 4; ++i) {                            \
      const int s = w * 4 + i;                                                 \
      gl16(&Bv[(size_t)(n0 + (s >> 1) * 16 + i16) * K + (kk) + (s & 1) * 32    \
               + q4 * 8],                                                      \
           &Bs[bufi][s * 512]); } }
#define LOAD_PFX(kk) {                                                         \
    _Pragma("unroll") for (int i = 0; i < 4; ++i) {                            \
      const float* src = Fp + (size_t)(m0 + arow + i * 32) * K + (kk) + akg;   \
      pf[i][0] = *(const float4*)src;                                          \
      pf[i][1] = *(const float4*)(src + 4); } }
#define CVT_X(bufi) {                                                          \
    _Pragma("unroll") for (int i = 0; i < 4; ++i) {                            \
      short8 v;                                                                \
      v[0] = (short)f2bf(pf[i][0].x); v[1] = (short)f2bf(pf[i][0].y);          \
      v[2] = (short)f2bf(pf[i][0].z); v[3] = (short)f2bf(pf[i][0].w);          \
      v[4] = (short)f2bf(pf[i][1].x); v[5] = (short)f2bf(pf[i][1].y);          \
      v[6] = (short)f2bf(pf[i][1].z); v[7] = (short)f2bf(pf[i][1].w);          \
      *(short8*)&As[bufi][(arow + i * 32) * 72 + akg] = v; } }

  const int nk = K >> 6;
  // prologue: tile 0 -> buf 0
  if constexpr (MODE == 1) {
    LOAD_PFX(0); STAGE_B16(0, 0); CVT_X(0); LOAD_PFX(64);
  } else {
    STAGE_A16(0, 0); STAGE_B16(0, 0);
  }
  __syncthreads();

  for (int t = 0; t < nk; ++t) {
    const int cur = t & 1, nxt = cur ^ 1;
    const int k1 = (t + 1) << 6;
    if (t + 1 < nk) {
      if constexpr (MODE == 1) {
        STAGE_B16(nxt, k1); CVT_X(nxt);
        if (t + 2 < nk) LOAD_PFX(k1 + 64);
      } else {
        STAGE_A16(nxt, k1); STAGE_B16(nxt, k1);
      }
    }
#pragma unroll
    for (int ks = 0; ks < 2; ++ks) {
      short8 af[MI], bfr[4];
#pragma unroll
      for (int mi = 0; mi < MI; ++mi) {
        if constexpr (MODE == 1)
          af[mi] = *(short8*)&As[cur][(wm + mi * 16 + i16) * 72 + ks * 32 + q4 * 8];
        else
          af[mi] = *(short8*)((char*)&As[cur][0] +
                              (((wm >> 4) + mi) * 2 + ks) * 1024 + l * 16);
      }
#pragma unroll
      for (int ni = 0; ni < 4; ++ni)
        bfr[ni] = *(short8*)((char*)&Bs[cur][0] +
                             (((wn >> 4) + ni) * 2 + ks) * 1024 + l * 16);
#pragma unroll
      for (int mi = 0; mi < MI; ++mi)
#pragma unroll
        for (int ni = 0; ni < 4; ++ni)
          acc[mi][ni] = mfma16(af[mi], bfr[ni], acc[mi][ni]);
    }
    __syncthreads();
  }
#undef STAGE_A16
#undef STAGE_B16
#undef LOAD_PFX
#undef CVT_X

  if constexpr (MODE == 0) {
    float* dstf = (float*)C0v;
    for (int mi = 0; mi < MI; ++mi) {
      int row = m0 + wm + mi * 16 + q4 * 4;
      for (int ni = 0; ni < 4; ++ni) {
        int nl = wn + ni * 16 + i16;
        for (int r = 0; r < 4; ++r)
          dstf[(size_t)(row + r) * N + n0 + nl] = acc[mi][ni][r];
      }
    }
  } else {
    for (int mi = 0; mi < MI; ++mi) {
      int row = m0 + wm + mi * 16 + q4 * 4;
      for (int ni = 0; ni < 4; ++ni) {
        int nl = wn + ni * 16 + i16;
        float b = bias[n0 + nl];
        if (n0 < 1024) {                 // Q tiled over [4096 tok][1024 d]
          u16* Qt = (u16*)C0v;
          const int d = n0 + nl;
          const int dt = d >> 6, dh = d & 63;
          const int sc = (dh >> 5), sl = (((dh & 31) >> 3) << 4), j = dh & 7;
          for (int r = 0; r < 4; ++r) {
            const int tok = row + r;
            size_t addr = ((size_t)((tok >> 6) * 16 + dt)) * 4096
                        + ((((tok & 63) >> 4) << 1) + sc) * 512
                        + ((tok & 15) + sl) * 8 + j;
            Qt[addr] = f2bf(acc[mi][ni][r] + b);
          }
        } else if (n0 < 2048) {          // K tiled (R9-verified formula)
          u16* KT = (u16*)C1v;
          const int d = (n0 - 1024) + nl;
          const int hh = d >> 6, dh = d & 63;
          const int sd = (dh >> 4) << 1;
          const int lh = ((dh >> 3) & 1) << 5;
          const int j = dh & 7;
          for (int r = 0; r < 4; ++r) {
            const int tok = row + r;
            const int bb = tok >> 11, t = tok & 2047;
            size_t addr = ((size_t)((bb << 4) + hh) * 32 + (t >> 6)) * 4096
                        + (sd + ((t >> 5) & 1)) * 512 + (lh + (t & 31)) * 8 + j;
            KT[addr] = f2bf(acc[mi][ni][r] + b);
          }
        } else {                         // V^T tiled (R9 MODE-2 formula, col-bias)
          u16* VTt = (u16*)C2v;
          const int d = (n0 - 2048) + nl;
          const int hh = d >> 6, dh = d & 63;
          for (int r = 0; r < 4; ++r) {
            const int tok = row + r;
            const int bb = tok >> 11, t = tok & 2047;
            size_t addr = ((size_t)((bb << 4) + hh) * 32 + (t >> 6)) * 4096
                        + ((((t & 63) >> 4) << 1) + (dh >> 5)) * 512
                        + ((((t >> 3) & 1) << 5) + (dh & 31)) * 8 + (t & 7);
            VTt[addr] = f2bf(acc[mi][ni][r] + b);
          }
        }
      }
    }
  }
}

// ---- flash attention: R9-verified body; Q read TILED, O written TILED ----
__global__ __launch_bounds__(512, 4) void attn_flash(u16* __restrict__ Qbuf,
                                                     const u16* __restrict__ Kall,
                                                     const u16* __restrict__ VTall) {
  constexpr float CSC = 0.18033688011112042f;   // log2(e)/sqrt(64)
  constexpr float MC  = 96.0f * CSC;            // fixed max (raw units) * CSC
  __shared__ __align__(16) u16 SH[32768];       // 64 KB staging ∪ 36864 B merge
  __shared__ float RsumB[128], RsumT[128];

  const int tid = threadIdx.x;
  const int w = tid >> 6, l = tid & 63;
  const int l31 = l & 31, hi = l >> 5;
  const int qg = w >> 1, th = w & 1;

  u16* KsL = SH + th * 16384;        // [2 buf][8 seg][512] u16
  u16* VsL = SH + th * 16384 + 8192; // [2 buf][8 seg][512] u16

  const int L = blockIdx.x;
  const int xcd = L & 7, rr = L >> 3;
  const int qb = rr & 15, gg = rr >> 4;
  const int g = gg * 8 + xcd;                   // 0..31 bijective
  const int h = g & 15, bat = g >> 4;
  const int q0 = qb * 128;

  u16* Q = Qbuf + (size_t)bat * 2048 * 1024;    // bat offset is tile-aligned
  const u16* ksrc = Kall + (size_t)((bat << 4) + h) * 131072 + l * 8;
  const u16* vsrc = VTall + (size_t)((bat << 4) + h) * 131072 + l * 8;

  // Q fragments from TILED layout: element (tok=q0+qg*32+l31, d=h*64+ks*16+hi*8+j)
  short8 qf[4];
  {
    const int mt = (q0 >> 6) + (qg >> 1);
    const u16* qtile = Q + ((size_t)mt * 16 + h) * 4096;
    const int rg = (qg & 1) * 2 + (l31 >> 4);       // (tok&63)>>4
#pragma unroll
    for (int ks = 0; ks < 4; ++ks) {
      const int s = rg * 2 + (ks >> 1);
      const int slot = (l31 & 15) + ((((ks & 1) << 1) + hi) << 4);
      qf[ks] = *(const short8*)(qtile + s * 512 + slot * 8);
    }
  }

#define STAGE(buf_, it_) {                                                   \
    const size_t toff = (size_t)(it_) * 4096;                                \
    gl16(ksrc + toff + qg * 512,       KsL + (buf_) * 4096 + qg * 512);      \
    gl16(ksrc + toff + (qg + 4) * 512, KsL + (buf_) * 4096 + (qg + 4) * 512);\
    gl16(vsrc + toff + qg * 512,       VsL + (buf_) * 4096 + qg * 512);      \
    gl16(vsrc + toff + (qg + 4) * 512, VsL + (buf_) * 4096 + (qg + 4) * 512); }

  f32x16 o0 = {}, o1 = {};
  float sm0 = 0.f, sm1 = 0.f, sm2 = 0.f, sm3 = 0.f;

  const int tbase = th * 16;                    // tile index base
  STAGE(0, tbase);
  __syncthreads();

  for (int i = 0; i < 16; ++i) {
    const int cur = i & 1;
    if (i + 1 < 16) STAGE(cur ^ 1, tbase + i + 1);

    const char* Kc = (const char*)KsL + cur * 8192 + l * 16;
    const char* Vc = (const char*)VsL + cur * 8192 + l * 16;

    // S^T = K @ Q^T : st{0,1}[reg] = S[q=l31][t = Tb*32 + (reg&3)+8*(reg>>2)+4*hi]
    f32x16 st0 = {}, st1 = {};
    __builtin_amdgcn_s_setprio(1);
#pragma unroll
    for (int ks = 0; ks < 4; ++ks) {
      short8 kf0 = *(const short8*)(Kc + ks * 2048);
      short8 kf1 = *(const short8*)(Kc + ks * 2048 + 1024);
      st0 = mfma32(kf0, qf[ks], st0);
      st1 = mfma32(kf1, qf[ks], st1);
    }
    __builtin_amdgcn_s_setprio(0);

    // softmax numerator p = 2^(s*CSC - MC); row-sum; pack bf16 pairs.
    u32 W[16];
#define SOFTMAX_PACK(stt, WB) {                                             \
      float p_[16];                                                         \
      _Pragma("unroll") for (int r = 0; r < 16; ++r)                        \
          p_[r] = fexp2(__builtin_fmaf(stt[r], CSC, -MC));                  \
      _Pragma("unroll") for (int r = 0; r < 16; r += 4) {                   \
        sm0 += p_[r]; sm1 += p_[r + 1]; sm2 += p_[r + 2]; sm3 += p_[r + 3]; \
      }                                                                     \
      _Pragma("unroll") for (int m = 0; m < 4; ++m)                         \
        _Pragma("unroll") for (int s = 0; s < 2; ++s)                       \
          asm("v_cvt_pk_bf16_f32 %0, %1, %2"                                \
              : "=v"(W[(WB) + m * 2 + s])                                   \
              : "v"(p_[4 * m + 2 * s]), "v"(p_[4 * m + 2 * s + 1]));        \
    }
    SOFTMAX_PACK(st0, 0)
    SOFTMAX_PACK(st1, 8)
#undef SOFTMAX_PACK

    // O += P @ V ; A-frag for t-step u via permlane32_swap of packed pairs
    __builtin_amdgcn_s_setprio(1);
#pragma unroll
    for (int u = 0; u < 4; ++u) {
      const int base = (u >> 1) * 8 + (u & 1) * 4;
      u32 a0 = W[base], a1 = W[base + 1], b0 = W[base + 2], b1 = W[base + 3];
      asm("v_permlane32_swap_b32 %0, %1" : "+v"(a0), "+v"(b0));
      asm("v_permlane32_swap_b32 %0, %1" : "+v"(a1), "+v"(b1));
      int4 af4;
      af4.x = (int)a0; af4.y = (int)a1; af4.z = (int)b0; af4.w = (int)b1;
      const short8 pfr = __builtin_bit_cast(short8, af4);
      const short8 vf0 = *(const short8*)(Vc + u * 2048);
      const short8 vf1 = *(const short8*)(Vc + u * 2048 + 1024);
      o0 = mfma32(pfr, vf0, o0);
      o1 = mfma32(pfr, vf1, o1);
    }
    __builtin_amdgcn_s_setprio(0);
    __syncthreads();   // drains next-tile gl16 (in flight all compute) + buf reuse
  }
#undef STAGE

  // ---- split-t merge: O = O_th0 + O_th1, rs = rs0 + rs1 (fixed max => pure add) ----
  float rs = (sm0 + sm1) + (sm2 + sm3);
  rs += __shfl_xor(rs, 32);
  __syncthreads();                                // staging LDS now dead
  float* MF = (float*)SH;                         // 256 lanes * 36 floats = 36864 B
  if (th == 1) {
    float* dst = MF + (qg * 64 + l) * 36;
    *(f32x16*)dst = o0;
    *(f32x16*)(dst + 16) = o1;
    if (hi == 0) RsumB[qg * 32 + l31] = rs;
  }
  __syncthreads();
  if (th == 0) {
    const float* src = MF + (qg * 64 + l) * 36;
    o0 += *(const f32x16*)src;
    o1 += *(const f32x16*)(src + 16);
    float rtot = rs + RsumB[qg * 32 + l31];
    if (hi == 0) RsumT[qg * 32 + l31] = rtot;
  }
  __syncthreads();
  if (th == 0) {
    // O overwrites Q in TILED layout; block touches only tiles (q0/64 + {0,1}, h)
    // which only THIS block reads as Q -> race-free.
#pragma unroll
    for (int r = 0; r < 16; ++r) {
      const int qq = (r & 3) + 8 * (r >> 2) + 4 * hi;
      const float inv = 1.0f / RsumT[qg * 32 + qq];
      const int tok = q0 + qg * 32 + qq;
      u16* ot = Q + ((size_t)(tok >> 6) * 16 + h) * 4096;
      const int sbase = (((tok & 63) >> 4) << 1);
      const int slot = ((tok & 15) + ((l31 >> 3) << 4)) * 8 + (l31 & 7);
      ot[sbase * 512 + slot]         = f2bf(o0[r] * inv);   // dh = l31
      ot[(sbase + 1) * 512 + slot]   = f2bf(o1[r] * inv);   // dh = 32 + l31
    }
  }
}

// ---------------- launcher ----------------
// inputs fp32: X [4096][1024], Wqkv [1024][3072], bqkv [3072], Wout [1024][1024]
// d_out (16 MB): [0,8M) Q/O TILED bf16 | [8,14M) WT1 | [14,16M) WT2
// ws (16 MB): [0,8M) V^T tiled | [8,16M) K tiled; reused as fp32 C after attention.
extern "C" void kernel_launch(void* const* d_in, const int* in_sizes, int n_in,
                              void* d_out, int out_size, void* d_ws, size_t ws_size,
                              hipStream_t stream) {
  const float* X    = (const float*)d_in[0];
  const float* Wqkv = (const float*)d_in[1];
  const float* bqkv = (const float*)d_in[2];
  const float* Wout = (const float*)d_in[3];

  u16* Qt   = (u16*)d_out;                       // Q/O tiled, 8 MB
  u16* WT1  = Qt + (size_t)4096 * 1024;          // [3072][1024] bf16 (Wqkv^T)
  u16* WT2  = WT1 + (size_t)3072 * 1024;         // [1024][1024] bf16 (Wout^T)
  u16* VTt  = (u16*)d_ws;                        // V^T tiled, 8 MB
  u16* Kt   = (u16*)d_ws + (size_t)4096 * 1024;  // K tiled, 8 MB
  float* Cws = (float*)d_ws;                     // [4096][1024] f32 (after attn)

  transpose_f32_bf16<<<dim3(96, 32), 256, 0, stream>>>(Wqkv, WT1, 1024, 3072);
  transpose_f32_bf16<<<dim3(32, 32), 256, 0, stream>>>(Wout, WT2, 1024, 1024);

  // fused QKV: [4096][3072] = X @ Wqkv; routes Q tiled / K tiled / V^T tiled
  gemm_bt<1, 128><<<dim3(24, 32), 256, 0, stream>>>(
      X, WT1, bqkv, Qt, Kt, VTt, 4096, 3072, 1024);

  attn_flash<<<dim3(512), 512, 0, stream>>>(Qt, Kt, VTt);

  // out-proj: O(tiled) @ Wout^T -> f32
  gemm_bt<0, 64><<<dim3(8, 64), 256, 0, stream>>>(
      Qt, WT2, nullptr, Cws, nullptr, nullptr, 4096, 1024, 1024);

  hipMemcpyAsync(d_out, Cws, (size_t)4096 * 1024 * sizeof(float),
                 hipMemcpyDeviceToDevice, stream);
}